// Round 4
// baseline (3589.706 us; speedup 1.0000x reference)
//
#include <hip/hip_runtime.h>

#define DEV __device__ __forceinline__

typedef _Float16 f16;
typedef _Float16 f16x8 __attribute__((ext_vector_type(8)));
typedef float f32x4 __attribute__((ext_vector_type(4)));

static constexpr int K0P  = 416;   // layer0 input dim 400 padded to 13*32
static constexpr int NBLK = 13;    // blocks per direction (13*32 = 416 >= 400 units)
static constexpr int GN   = 3328;  // permuted gate cols = 2*13*128
static constexpr int WKP  = 424;   // padded K for W LDS rows
static constexpr int SMEM_LSTM = 128 * WKP * 2;      // 108,544 B
static constexpr int HB_BYTES  = 2 * 2 * 13 * 1024 * 2;  // [d][phase][kk][half*512+lane*8+e] f16

// ---------------- math helpers ----------------
DEV float sigf(float x) { return 1.f / (1.f + __expf(-x)); }
DEV float tanhf_(float x) {
  x = fminf(10.f, fmaxf(-10.f, x));
  float e = __expf(2.f * x);
  return (e - 1.f) / (e + 1.f);
}

// ---------------- embedding gather -> x0 f16 [4096][416] ----------------
__global__ void embed_k(const int* __restrict__ wt, const int* __restrict__ pt,
                        const float* __restrict__ we, const float* __restrict__ pe,
                        f16* __restrict__ x0)
{
  const int r = blockIdx.x;
  const int tid = threadIdx.x;
  const int w = wt[r], p = pt[r];
  const float* wrow = we + (size_t)w * 300;
  const float* prow = pe + (size_t)p * 100;
  f16* xr = x0 + (size_t)r * K0P;
  for (int k = tid; k < K0P; k += 128) {
    float v = (k < 300) ? wrow[k] : (k < 400 ? prow[k - 300] : 0.f);
    xr[k] = (f16)v;
  }
}

// ---------------- f32 -> f16 with optional K padding ----------------
__global__ void convpad_k(const float* __restrict__ src, f16* __restrict__ dst,
                          int rows, int K, int KP)
{
  const size_t total = (size_t)rows * KP;
  for (size_t i = (size_t)blockIdx.x * blockDim.x + threadIdx.x; i < total;
       i += (size_t)gridDim.x * blockDim.x) {
    int r = (int)(i / KP), k = (int)(i % KP);
    dst[i] = (f16)(k < K ? src[(size_t)r * K + k] : 0.f);
  }
}

// Wih f32 [2][1600][K] + bias [2][1600] -> permuted f16 [GN][KP] + biasr [GN]
// row R = d*1664 + blk*128 + loc; loc = w*32 + slot*4 + gate; unit u = blk*32 + w*8 + slot
__global__ void wih_reorder_k(const float* __restrict__ src, const float* __restrict__ bias,
                              f16* __restrict__ dst, float* __restrict__ biasr,
                              int K, int KP)
{
  const size_t total = (size_t)GN * KP;
  for (size_t i = (size_t)blockIdx.x * blockDim.x + threadIdx.x; i < total;
       i += (size_t)gridDim.x * blockDim.x) {
    int k = (int)(i % KP);
    int R = (int)(i / KP);
    int d = R / 1664, rr = R % 1664, blk = rr >> 7, loc = rr & 127;
    int w = loc >> 5, s8 = (loc >> 2) & 7, g = loc & 3;
    int u = blk * 32 + w * 8 + s8;
    float v = (u < 400 && k < K) ? src[((size_t)d * 1600 + g * 400 + u) * K + k] : 0.f;
    dst[i] = (f16)v;
    if (k == 0) biasr[R] = (u < 400) ? bias[d * 1600 + g * 400 + u] : 0.f;
  }
}

// Whh f32 [2][1600][400] -> reordered f16 [2][NBLK][128][WKP] (same row permutation)
__global__ void whh_reorder_k(const float* __restrict__ src, f16* __restrict__ dst)
{
  const int total = 2 * NBLK * 128 * WKP;
  for (int i = blockIdx.x * blockDim.x + threadIdx.x; i < total;
       i += gridDim.x * blockDim.x) {
    int k = i % WKP, loc = (i / WKP) & 127, blk = (i / (WKP * 128)) % NBLK,
        d = i / (WKP * 128 * NBLK);
    int w = loc >> 5, s8 = (loc >> 2) & 7, g = loc & 3;
    int u = blk * 32 + w * 8 + s8;
    float v = (u < 400 && k < 400) ? src[((size_t)d * 1600 + g * 400 + u) * 400 + k] : 0.f;
    dst[i] = (f16)v;
  }
}

__global__ void biascat_k(const float* __restrict__ bh, const float* __restrict__ bm,
                          float* __restrict__ bhm)
{
  int i = threadIdx.x;
  bhm[i] = i < 512 ? bh[i] : bm[i - 512];
}

__global__ void zero_k(int* __restrict__ p, int n)
{
  for (int i = blockIdx.x * blockDim.x + threadIdx.x; i < n; i += gridDim.x * blockDim.x)
    p[i] = 0;
}

// ---------------- GEMM: C[M][N] = A[M][KP] * B[N][KP]^T + bias[n] ----------------
__global__ __launch_bounds__(256) void gemm_f16_nt(
    const f16* __restrict__ A, const f16* __restrict__ Bw,
    const float* __restrict__ bias, float* __restrict__ C,
    int M, int N, int KP)
{
  __shared__ __align__(16) f16 As[128][40];
  __shared__ __align__(16) f16 Bs[128][40];
  const int tid = threadIdx.x;
  const int bn = blockIdx.x, bm = blockIdx.y;
  const int lane = tid & 63, wid = tid >> 6;
  const int wr = wid >> 1, wc = wid & 1;
  const int srow = tid >> 1, shalf = tid & 1;
  const f16* Ap = A + (size_t)(bm * 128 + srow) * KP + shalf * 16;
  const f16* Bp = Bw + (size_t)(bn * 128 + srow) * KP + shalf * 16;
  const int fr = lane & 15, fq = lane >> 4;
  f32x4 acc[4][4] = {};
  for (int kt = 0; kt < KP; kt += 32) {
    __syncthreads();
    *(uint4*)&As[srow][shalf * 16]     = *(const uint4*)(Ap + kt);
    *(uint4*)&As[srow][shalf * 16 + 8] = *(const uint4*)(Ap + kt + 8);
    *(uint4*)&Bs[srow][shalf * 16]     = *(const uint4*)(Bp + kt);
    *(uint4*)&Bs[srow][shalf * 16 + 8] = *(const uint4*)(Bp + kt + 8);
    __syncthreads();
    f16x8 af[4], bf[4];
    #pragma unroll
    for (int m = 0; m < 4; ++m) af[m] = *(const f16x8*)&As[wr * 64 + m * 16 + fr][fq * 8];
    #pragma unroll
    for (int n = 0; n < 4; ++n) bf[n] = *(const f16x8*)&Bs[wc * 64 + n * 16 + fr][fq * 8];
    #pragma unroll
    for (int m = 0; m < 4; ++m)
      #pragma unroll
      for (int n = 0; n < 4; ++n)
        acc[m][n] = __builtin_amdgcn_mfma_f32_16x16x32_f16(af[m], bf[n], acc[m][n], 0, 0, 0);
  }
  #pragma unroll
  for (int n = 0; n < 4; ++n) {
    const int gn = bn * 128 + wc * 64 + n * 16 + fr;
    const float bv = bias ? bias[gn] : 0.f;
    #pragma unroll
    for (int m = 0; m < 4; ++m) {
      const size_t gm = (size_t)bm * 128 + wr * 64 + m * 16 + fq * 4;
      #pragma unroll
      for (int r = 0; r < 4; ++r)
        C[(gm + r) * (size_t)N + gn] = acc[m][n][r] + bv;
    }
  }
}

// ---------------- recurrence: 26 worker blocks = 2 dirs x 13 slices ----------------
// gates [4096][GN] f32 (permuted cols, bias included)
// whh_r [2][NBLK][128][WKP] f16 ; hB ring [2][2][13][2][64][8] f16 (pre-zeroed)
// flags [2][128][64] (52 used); ctrl {pool0,pool1,checkin}
__global__ __launch_bounds__(256) void lstm_mfma_k(
    const float* __restrict__ gates,
    const f16* __restrict__ whh_r,
    f16* __restrict__ h_out,
    f16* __restrict__ hB,
    int* __restrict__ flags,
    int* __restrict__ ctrl)
{
  extern __shared__ __align__(16) char smem[];
  f16* W_lds = (f16*)smem;                 // [128][WKP]
  __shared__ int role_sh;

  const int tid = threadIdx.x;
  const int lane = tid & 63, w = tid >> 6;
  const int fr = lane & 15, fq = lane >> 4;

  // ---- claim a (dir, slice) role with XCD affinity; scavenge fallback ----
  if (tid == 0) {
    int xcc;
    asm volatile("s_getreg_b32 %0, hwreg(HW_REG_XCC_ID)" : "=s"(xcc));
    xcc &= 7;
    int role = -1;
    if (xcc < 2) {
      int r = atomicAdd(&ctrl[xcc], 1);
      if (r < NBLK) role = xcc * NBLK + r;
    }
    __hip_atomic_fetch_add(&ctrl[2], 1, __ATOMIC_RELAXED, __HIP_MEMORY_SCOPE_AGENT);
    if (role < 0) {
      while (__hip_atomic_load(&ctrl[2], __ATOMIC_RELAXED, __HIP_MEMORY_SCOPE_AGENT)
             < (int)gridDim.x)
        __builtin_amdgcn_s_sleep(8);
      for (int dd = 0; dd < 2 && role < 0; ++dd) {
        int r = atomicAdd(&ctrl[dd], 1);
        if (r < NBLK) role = dd * NBLK + r;
      }
    }
    role_sh = role;
  }
  __syncthreads();
  const int role = role_sh;
  if (role < 0) return;
  const int d = role / NBLK, blk = role % NBLK;

  // ---- W slice -> LDS once ----
  {
    const uint4* src = (const uint4*)(whh_r + ((size_t)d * NBLK + blk) * 128 * WKP);
    uint4* dst = (uint4*)W_lds;
    for (int i = tid; i < 128 * WKP / 8; i += 256) dst[i] = src[i];
  }
  __syncthreads();

  // per-lane constants
  const int u0 = blk * 32 + w * 8 + fq;     // tile0 unit
  const int u1 = u0 + 4;                    // tile1 unit
  const bool ok0 = u0 < 400, ok1 = u1 < 400;
  const float* gbase0 = gates + (size_t)(fr * 128) * GN + d * 1664 + blk * 128 + w * 32;
  const float* gbase1 = gbase0 + (size_t)16 * 128 * GN;
  f16* hout0 = h_out + (size_t)(fr * 128) * 800 + d * 400;
  f16* hout1 = hout0 + (size_t)16 * 128 * 800;
  const f16* a0base = W_lds + (size_t)(w * 32 + fr) * WKP + fq * 8;
  const f16* a1base = a0base + 16 * WKP;
  int* flg_d = flags + (d << 13);           // d*128*64
  f16* hb_d = hB + (size_t)d * 2 * 13 * 1024;

  float c00 = 0.f, c01 = 0.f, c10 = 0.f, c11 = 0.f;

  for (int s = 0; s < 128; ++s) {
    const int t = d ? 127 - s : s;
    // prefetch gate inputs (i,f,g,o packed per unit by the Wih permutation)
    const float* g0 = gbase0 + (size_t)t * GN;
    const float* g1 = gbase1 + (size_t)t * GN;
    float4 p00 = *(const float4*)(g0 + fq * 4);
    float4 p10 = *(const float4*)(g0 + 16 + fq * 4);
    float4 p01 = *(const float4*)(g1 + fq * 4);
    float4 p11 = *(const float4*)(g1 + 16 + fq * 4);

    f32x4 acc00 = {}, acc01 = {}, acc10 = {}, acc11 = {};
    if (s > 0) {
      if (w == 0) {  // leader wave polls all 52 producer flags in parallel
        const int* fl = flg_d + ((s - 1) << 6);
        for (;;) {
          int f = (lane < 4 * NBLK)
                    ? __hip_atomic_load(fl + lane, __ATOMIC_RELAXED, __HIP_MEMORY_SCOPE_AGENT)
                    : 1;
          if (~__ballot(f != 0) == 0ull) break;
        }
        __builtin_amdgcn_fence(__ATOMIC_ACQUIRE, "agent");
      }
      __syncthreads();
      // coalesced fragment loads from the hB ring (L2-resident, 26 x 16B/lane)
      const f16* hb = hb_d + (size_t)((s - 1) & 1) * 13 * 1024 + lane * 8;
      f16x8 bf0[13], bf1[13];
      #pragma unroll
      for (int kk = 0; kk < 13; ++kk) {
        bf0[kk] = *(const f16x8*)(hb + kk * 1024);
        bf1[kk] = *(const f16x8*)(hb + kk * 1024 + 512);
      }
      #pragma unroll
      for (int kk = 0; kk < 13; ++kk) {
        f16x8 a0 = *(const f16x8*)(a0base + kk * 32);
        f16x8 a1 = *(const f16x8*)(a1base + kk * 32);
        acc00 = __builtin_amdgcn_mfma_f32_16x16x32_f16(a0, bf0[kk], acc00, 0, 0, 0);
        acc01 = __builtin_amdgcn_mfma_f32_16x16x32_f16(a0, bf1[kk], acc01, 0, 0, 0);
        acc10 = __builtin_amdgcn_mfma_f32_16x16x32_f16(a1, bf0[kk], acc10, 0, 0, 0);
        acc11 = __builtin_amdgcn_mfma_f32_16x16x32_f16(a1, bf1[kk], acc11, 0, 0, 0);
      }
    } else {
      __syncthreads();
    }

    // in-register activations: acc reg r = gate r (i,f,g,o) of one unit
    auto act = [&](const f32x4& a, const float4& p, float& c) -> f16 {
      float vi = a[0] + p.x, vf = a[1] + p.y, vg = a[2] + p.z, vo = a[3] + p.w;
      c = sigf(vf) * c + sigf(vi) * tanhf_(vg);
      return (f16)(sigf(vo) * tanhf_(c));
    };
    f16 h00 = act(acc00, p00, c00);
    f16 h01 = act(acc01, p01, c01);
    f16 h10 = act(acc10, p10, c10);
    f16 h11 = act(acc11, p11, c11);

    // publish h in fragment order + row-major for the next GEMM
    f16* hbw = hb_d + (size_t)(s & 1) * 13 * 1024 + blk * 1024 + (w * 16 + fr) * 8;
    if (ok0) {
      hbw[fq] = h00; hbw[512 + fq] = h01;
      hout0[(size_t)t * 800 + u0] = h00;
      hout1[(size_t)t * 800 + u0] = h01;
    }
    if (ok1) {
      hbw[4 + fq] = h10; hbw[512 + 4 + fq] = h11;
      hout0[(size_t)t * 800 + u1] = h10;
      hout1[(size_t)t * 800 + u1] = h11;
    }
    if (lane == 0)
      __hip_atomic_store(flg_d + (s << 6) + blk * 4 + w, 1, __ATOMIC_RELEASE,
                         __HIP_MEMORY_SCOPE_AGENT);
  }
}

// ---------------- tail ----------------
__global__ __launch_bounds__(256) void tail_k(const float* __restrict__ feat,
                                              const float* __restrict__ wo,
                                              float* __restrict__ s_h,
                                              float* __restrict__ s_m)
{
  const int r = blockIdx.x;
  const int tid = threadIdx.x;
  const float* fr = feat + (size_t)r * 1024;
  float sum = 0.f;
  const int n0 = tid * 4;
  #pragma unroll
  for (int j = 0; j < 4; ++j) sum += tanhf_(fr[n0 + j]) * wo[n0 + j];
  #pragma unroll
  for (int off = 32; off > 0; off >>= 1) sum += __shfl_down(sum, off, 64);
  __shared__ float red[4];
  if ((tid & 63) == 0) red[tid >> 6] = sum;
  __syncthreads();
  if (tid == 0)       s_h[r] = red[0] + red[1];
  else if (tid == 64) s_m[r] = red[2] + red[3];
}

__global__ void score_k(const float* __restrict__ s_h, const float* __restrict__ s_m,
                        const float* __restrict__ bo, float* __restrict__ out)
{
  const int bh = blockIdx.x;
  const int m = threadIdx.x;
  out[(size_t)bh * 128 + m] = s_h[bh] + s_m[(bh & ~127) + m] + bo[0];
}

// ---------------- launch ----------------
extern "C" void kernel_launch(void* const* d_in, const int* in_sizes, int n_in,
                              void* d_out, int out_size, void* d_ws, size_t ws_size,
                              hipStream_t stream)
{
  const int*   wt   = (const int*)d_in[0];
  const int*   pt   = (const int*)d_in[2];
  const float* we   = (const float*)d_in[3];
  const float* pe   = (const float*)d_in[4];
  const float* Wih0 = (const float*)d_in[5];
  const float* Whh0 = (const float*)d_in[6];
  const float* b0   = (const float*)d_in[7];
  const float* Wih1 = (const float*)d_in[8];
  const float* Whh1 = (const float*)d_in[9];
  const float* b1   = (const float*)d_in[10];
  const float* Wh   = (const float*)d_in[11];
  const float* bh   = (const float*)d_in[12];
  const float* Wm   = (const float*)d_in[13];
  const float* bm   = (const float*)d_in[14];
  const float* Wo   = (const float*)d_in[15];
  const float* bo   = (const float*)d_in[16];
  float* out = (float*)d_out;

  char* p = (char*)d_ws;
  auto alloc = [&](size_t bytes) { char* q = p; p += (bytes + 255) & ~(size_t)255; return q; };
  f16*   x0    = (f16*)alloc((size_t)4096 * K0P * 2);
  f16*   wihr0 = (f16*)alloc((size_t)GN * K0P * 2);
  f16*   wihr1 = (f16*)alloc((size_t)GN * 800 * 2);
  f16*   whhr0 = (f16*)alloc((size_t)2 * NBLK * 128 * WKP * 2);
  f16*   whhr1 = (f16*)alloc((size_t)2 * NBLK * 128 * WKP * 2);
  f16*   whm   = (f16*)alloc((size_t)1024 * 800 * 2);
  float* biasr0= (float*)alloc(GN * 4);
  float* biasr1= (float*)alloc(GN * 4);
  float* bhm   = (float*)alloc(1024 * 4);
  float* sh    = (float*)alloc(4096 * 4);
  float* sm    = (float*)alloc(4096 * 4);
  f16*   h1    = (f16*)alloc((size_t)4096 * 800 * 2);
  f16*   h2    = (f16*)alloc((size_t)4096 * 800 * 2);
  int*   flg   = (int*)alloc((size_t)2 * 2 * 128 * 64 * 4);  // [layer][d][s][64]
  int*   ctrl  = (int*)alloc(128);                           // [layer][3]
  f16*   hB    = (f16*)alloc(HB_BYTES);
  float* gates = (float*)alloc((size_t)4096 * GN * 4);
  float* feat  = (float*)gates;   // gates dead before feature GEMM

  static bool attr_set = false;
  if (!attr_set) {
    hipFuncSetAttribute((const void*)lstm_mfma_k,
                        hipFuncAttributeMaxDynamicSharedMemorySize, SMEM_LSTM);
    attr_set = true;
  }

  // zero flags + ctrl + hB (contiguous allocations)
  {
    int zn = (int)(((char*)hB + HB_BYTES - (char*)flg) / 4);
    zero_k<<<512, 256, 0, stream>>>(flg, zn);
  }
  embed_k<<<4096, 128, 0, stream>>>(wt, pt, we, pe, x0);
  wih_reorder_k<<<1024, 256, 0, stream>>>(Wih0, b0, wihr0, biasr0, 400, K0P);
  wih_reorder_k<<<1024, 256, 0, stream>>>(Wih1, b1, wihr1, biasr1, 800, 800);
  whh_reorder_k<<<1024, 256, 0, stream>>>(Whh0, whhr0);
  whh_reorder_k<<<1024, 256, 0, stream>>>(Whh1, whhr1);
  convpad_k<<<1024, 256, 0, stream>>>(Wh, whm, 512, 800, 800);
  convpad_k<<<1024, 256, 0, stream>>>(Wm, whm + (size_t)512 * 800, 512, 800, 800);
  biascat_k<<<1, 1024, 0, stream>>>(bh, bm, bhm);

  // layer 0
  gemm_f16_nt<<<dim3(26, 32), 256, 0, stream>>>(x0, wihr0, biasr0, gates, 4096, GN, K0P);
  lstm_mfma_k<<<128, 256, SMEM_LSTM, stream>>>(gates, whhr0, h1, hB, flg, ctrl);
  // layer 1
  gemm_f16_nt<<<dim3(26, 32), 256, 0, stream>>>(h1, wihr1, biasr1, gates, 4096, GN, 800);
  lstm_mfma_k<<<128, 256, SMEM_LSTM, stream>>>(gates, whhr1, h2, hB,
                                               flg + 2 * 128 * 64, ctrl + 16);
  // features + scorer
  gemm_f16_nt<<<dim3(8, 32), 256, 0, stream>>>(h2, whm, bhm, feat, 4096, 1024, 800);
  tail_k<<<4096, 256, 0, stream>>>(feat, Wo, sh, sm);
  score_k<<<4096, 128, 0, stream>>>(sh, sm, bo, out);
}

// Round 5
// 1769.933 us; speedup vs baseline: 2.0282x; 2.0282x over previous
//
#include <hip/hip_runtime.h>

#define DEV __device__ __forceinline__

typedef _Float16 f16;
typedef _Float16 f16x8 __attribute__((ext_vector_type(8)));
typedef float f32x4 __attribute__((ext_vector_type(4)));
typedef unsigned long long ull;

static constexpr int K0P  = 416;   // layer0 input dim 400 padded to 13*32
static constexpr int NBLK = 13;    // blocks per direction (13*32 = 416 >= 400 units)
static constexpr int GN   = 3328;  // permuted gate cols = 2*13*128
static constexpr int WKP  = 424;   // padded K for W LDS rows (odd 16B segs -> conflict-free)
static constexpr int SMEM_LSTM = 128 * WKP * 2;          // 108,544 B (W only)
static constexpr int HB_BYTES  = 2 * 2 * 13 * 1024 * 2;  // [d][phase][blk][1024] f16

// ---------------- math helpers ----------------
DEV float sigf(float x) { return 1.f / (1.f + __expf(-x)); }
DEV float tanhf_(float x) {
  x = fminf(10.f, fmaxf(-10.f, x));
  float e = __expf(2.f * x);
  return (e - 1.f) / (e + 1.f);
}
DEV ull  AL8(const ull* p) { return __hip_atomic_load(p, __ATOMIC_RELAXED, __HIP_MEMORY_SCOPE_AGENT); }
DEV int  AL4(const int* p) { return __hip_atomic_load(p, __ATOMIC_RELAXED, __HIP_MEMORY_SCOPE_AGENT); }
DEV void AS4(unsigned* p, unsigned v) { __hip_atomic_store(p, v, __ATOMIC_RELAXED, __HIP_MEMORY_SCOPE_AGENT); }
DEV void ASI(int* p, int v) { __hip_atomic_store(p, v, __ATOMIC_RELAXED, __HIP_MEMORY_SCOPE_AGENT); }

// row permutation: loc in [0,128): w=loc>>5, t=(loc>>4)&1, fq=(loc>>2)&3, g=loc&3
// unit u = blk*32 + w*8 + 2*fq + t ; gate g (i,f,g,o)

// ---------------- embedding gather -> x0 f16 [4096][416] ----------------
__global__ void embed_k(const int* __restrict__ wt, const int* __restrict__ pt,
                        const float* __restrict__ we, const float* __restrict__ pe,
                        f16* __restrict__ x0)
{
  const int r = blockIdx.x;
  const int tid = threadIdx.x;
  const int w = wt[r], p = pt[r];
  const float* wrow = we + (size_t)w * 300;
  const float* prow = pe + (size_t)p * 100;
  f16* xr = x0 + (size_t)r * K0P;
  for (int k = tid; k < K0P; k += 128) {
    float v = (k < 300) ? wrow[k] : (k < 400 ? prow[k - 300] : 0.f);
    xr[k] = (f16)v;
  }
}

// ---------------- f32 -> f16 with optional K padding ----------------
__global__ void convpad_k(const float* __restrict__ src, f16* __restrict__ dst,
                          int rows, int K, int KP)
{
  const size_t total = (size_t)rows * KP;
  for (size_t i = (size_t)blockIdx.x * blockDim.x + threadIdx.x; i < total;
       i += (size_t)gridDim.x * blockDim.x) {
    int r = (int)(i / KP), k = (int)(i % KP);
    dst[i] = (f16)(k < K ? src[(size_t)r * K + k] : 0.f);
  }
}

// Wih f32 [2][1600][K] + bias -> permuted f16 [GN][KP] + biasr [GN]
__global__ void wih_reorder_k(const float* __restrict__ src, const float* __restrict__ bias,
                              f16* __restrict__ dst, float* __restrict__ biasr,
                              int K, int KP)
{
  const size_t total = (size_t)GN * KP;
  for (size_t i = (size_t)blockIdx.x * blockDim.x + threadIdx.x; i < total;
       i += (size_t)gridDim.x * blockDim.x) {
    int k = (int)(i % KP);
    int R = (int)(i / KP);
    int d = R / 1664, rr = R % 1664, blk = rr >> 7, loc = rr & 127;
    int w = loc >> 5, t = (loc >> 4) & 1, fq = (loc >> 2) & 3, g = loc & 3;
    int u = blk * 32 + w * 8 + 2 * fq + t;
    float v = (u < 400 && k < K) ? src[((size_t)d * 1600 + g * 400 + u) * K + k] : 0.f;
    dst[i] = (f16)v;
    if (k == 0) biasr[R] = (u < 400) ? bias[d * 1600 + g * 400 + u] : 0.f;
  }
}

// Whh f32 [2][1600][400] -> reordered f16 [2][NBLK][128][WKP]
__global__ void whh_reorder_k(const float* __restrict__ src, f16* __restrict__ dst)
{
  const int total = 2 * NBLK * 128 * WKP;
  for (int i = blockIdx.x * blockDim.x + threadIdx.x; i < total;
       i += gridDim.x * blockDim.x) {
    int k = i % WKP, loc = (i / WKP) & 127, blk = (i / (WKP * 128)) % NBLK,
        d = i / (WKP * 128 * NBLK);
    int w = loc >> 5, t = (loc >> 4) & 1, fq = (loc >> 2) & 3, g = loc & 3;
    int u = blk * 32 + w * 8 + 2 * fq + t;
    float v = (u < 400 && k < 400) ? src[((size_t)d * 1600 + g * 400 + u) * 400 + k] : 0.f;
    dst[i] = (f16)v;
  }
}

__global__ void biascat_k(const float* __restrict__ bh, const float* __restrict__ bm,
                          float* __restrict__ bhm)
{
  int i = threadIdx.x;
  bhm[i] = i < 512 ? bh[i] : bm[i - 512];
}

__global__ void zero_k(int* __restrict__ p, int n)
{
  for (int i = blockIdx.x * blockDim.x + threadIdx.x; i < n; i += gridDim.x * blockDim.x)
    p[i] = 0;
}

// ---------------- GEMM: C[M][N] = A[M][KP] * B[N][KP]^T + bias[n] ----------------
__global__ __launch_bounds__(256) void gemm_f16_nt(
    const f16* __restrict__ A, const f16* __restrict__ Bw,
    const float* __restrict__ bias, float* __restrict__ C,
    int M, int N, int KP)
{
  __shared__ __align__(16) f16 As[128][40];
  __shared__ __align__(16) f16 Bs[128][40];
  const int tid = threadIdx.x;
  const int bn = blockIdx.x, bm = blockIdx.y;
  const int lane = tid & 63, wid = tid >> 6;
  const int wr = wid >> 1, wc = wid & 1;
  const int srow = tid >> 1, shalf = tid & 1;
  const f16* Ap = A + (size_t)(bm * 128 + srow) * KP + shalf * 16;
  const f16* Bp = Bw + (size_t)(bn * 128 + srow) * KP + shalf * 16;
  const int fr = lane & 15, fq = lane >> 4;
  f32x4 acc[4][4] = {};
  for (int kt = 0; kt < KP; kt += 32) {
    __syncthreads();
    *(uint4*)&As[srow][shalf * 16]     = *(const uint4*)(Ap + kt);
    *(uint4*)&As[srow][shalf * 16 + 8] = *(const uint4*)(Ap + kt + 8);
    *(uint4*)&Bs[srow][shalf * 16]     = *(const uint4*)(Bp + kt);
    *(uint4*)&Bs[srow][shalf * 16 + 8] = *(const uint4*)(Bp + kt + 8);
    __syncthreads();
    f16x8 af[4], bf[4];
    #pragma unroll
    for (int m = 0; m < 4; ++m) af[m] = *(const f16x8*)&As[wr * 64 + m * 16 + fr][fq * 8];
    #pragma unroll
    for (int n = 0; n < 4; ++n) bf[n] = *(const f16x8*)&Bs[wc * 64 + n * 16 + fr][fq * 8];
    #pragma unroll
    for (int m = 0; m < 4; ++m)
      #pragma unroll
      for (int n = 0; n < 4; ++n)
        acc[m][n] = __builtin_amdgcn_mfma_f32_16x16x32_f16(af[m], bf[n], acc[m][n], 0, 0, 0);
  }
  #pragma unroll
  for (int n = 0; n < 4; ++n) {
    const int gn = bn * 128 + wc * 64 + n * 16 + fr;
    const float bv = bias ? bias[gn] : 0.f;
    #pragma unroll
    for (int m = 0; m < 4; ++m) {
      const size_t gm = (size_t)bm * 128 + wr * 64 + m * 16 + fq * 4;
      #pragma unroll
      for (int r = 0; r < 4; ++r)
        C[(gm + r) * (size_t)N + gn] = acc[m][n][r] + bv;
    }
  }
}

// ---------------- recurrence: 26 blocks = 2 dirs x 13 slices, barrier-free loop ----
// All cross-block traffic via relaxed agent atomics (point ops, no cache maintenance);
// ordering via s_waitcnt vmcnt(0) before flag store.
__global__ __launch_bounds__(256) void lstm_mfma_k(
    const float* __restrict__ gates,
    const f16* __restrict__ whh_r,
    f16* __restrict__ h_out,
    f16* __restrict__ hB,
    int* __restrict__ flags)
{
  extern __shared__ __align__(16) char smem[];
  f16* W_lds = (f16*)smem;                 // [128][WKP]

  const int d = blockIdx.x / NBLK, blk = blockIdx.x % NBLK;
  const int tid = threadIdx.x;
  const int lane = tid & 63, w = tid >> 6;
  const int fr = lane & 15, fq = lane >> 4;

  // W slice -> LDS once
  {
    const uint4* src = (const uint4*)(whh_r + ((size_t)d * NBLK + blk) * 128 * WKP);
    uint4* dst = (uint4*)W_lds;
    for (int i = tid; i < 128 * WKP / 8; i += 256) dst[i] = src[i];
  }
  __syncthreads();   // the only barrier; loop below is barrier-free

  // per-lane constants
  const int u0 = blk * 32 + w * 8 + 2 * fq;   // even; u1 = u0+1
  const bool ok = u0 < 400;
  const float* gbase0 = gates + (size_t)(fr * 128) * GN + d * 1664 + blk * 128 + w * 32;
  const float* gbase1 = gbase0 + (size_t)16 * 128 * GN;
  f16* hout0 = h_out + (size_t)(fr * 128) * 800 + d * 400;
  f16* hout1 = hout0 + (size_t)16 * 128 * 800;
  const f16* a0base = W_lds + (size_t)(w * 32 + fr) * WKP + fq * 8;
  const f16* a1base = a0base + 16 * WKP;
  int* flg_d = flags + (d << 13);                 // d*128*64
  f16* hb_d = hB + (size_t)d * 2 * 13 * 1024;

  float c00 = 0.f, c01 = 0.f, c10 = 0.f, c11 = 0.f;

  for (int s = 0; s < 128; ++s) {
    const int t = d ? 127 - s : s;
    // gate prefetch (plain cached loads; i,f,g,o packed per unit)
    const float* g0 = gbase0 + (size_t)t * GN;
    const float* g1 = gbase1 + (size_t)t * GN;
    float4 p00 = *(const float4*)(g0 + fq * 4);
    float4 p10 = *(const float4*)(g0 + 16 + fq * 4);
    float4 p01 = *(const float4*)(g1 + fq * 4);
    float4 p11 = *(const float4*)(g1 + 16 + fq * 4);

    f32x4 acc00 = {}, acc01 = {}, acc10 = {}, acc11 = {};
    if (s > 0) {
      // wave-parallel relaxed poll of 52 per-wave producer flags
      const int* fl = flg_d + ((s - 1) << 6);
      for (;;) {
        int f = (lane < 4 * NBLK) ? AL4(fl + lane) : 1;
        if (~__ballot(f != 0) == 0ull) break;
      }
      asm volatile("" ::: "memory");
      // 104 relaxed 8B point loads of the fragment-native hB slab
      const ull* hbq = (const ull*)(hb_d + (size_t)((s - 1) & 1) * 13 * 1024);
      ull qa0[13], qa1[13], qb0[13], qb1[13];
      #pragma unroll
      for (int kk = 0; kk < 13; ++kk) {
        const ull* pp = hbq + kk * 256 + lane * 2;
        qa0[kk] = AL8(pp);       qa1[kk] = AL8(pp + 1);
        qb0[kk] = AL8(pp + 128); qb1[kk] = AL8(pp + 129);
      }
      #pragma unroll
      for (int kk = 0; kk < 13; ++kk) {
        f16x8 a0 = *(const f16x8*)(a0base + kk * 32);
        f16x8 a1 = *(const f16x8*)(a1base + kk * 32);
        union { ull u[2]; f16x8 v; } B0, B1;
        B0.u[0] = qa0[kk]; B0.u[1] = qa1[kk];
        B1.u[0] = qb0[kk]; B1.u[1] = qb1[kk];
        acc00 = __builtin_amdgcn_mfma_f32_16x16x32_f16(a0, B0.v, acc00, 0, 0, 0);
        acc01 = __builtin_amdgcn_mfma_f32_16x16x32_f16(a0, B1.v, acc01, 0, 0, 0);
        acc10 = __builtin_amdgcn_mfma_f32_16x16x32_f16(a1, B0.v, acc10, 0, 0, 0);
        acc11 = __builtin_amdgcn_mfma_f32_16x16x32_f16(a1, B1.v, acc11, 0, 0, 0);
      }
    }

    // in-register activations: acc reg r = gate r (i,f,g,o) of one unit
    auto act = [&](const f32x4& a, const float4& p, float& c) -> f16 {
      float vi = a[0] + p.x, vf = a[1] + p.y, vg = a[2] + p.z, vo = a[3] + p.w;
      c = sigf(vf) * c + sigf(vi) * tanhf_(vg);
      return (f16)(sigf(vo) * tanhf_(c));
    };
    f16 h00 = act(acc00, p00, c00);   // (u0,   batch fr)
    f16 h10 = act(acc10, p10, c10);   // (u0+1, batch fr)
    f16 h01 = act(acc01, p01, c01);   // (u0,   batch fr+16)
    f16 h11 = act(acc11, p11, c11);   // (u0+1, batch fr+16)

    if (ok) {
      unsigned pk0 = (unsigned)__builtin_bit_cast(unsigned short, h00) |
                     ((unsigned)__builtin_bit_cast(unsigned short, h10) << 16);
      unsigned pk1 = (unsigned)__builtin_bit_cast(unsigned short, h01) |
                     ((unsigned)__builtin_bit_cast(unsigned short, h11) << 16);
      unsigned* hbw = (unsigned*)(hb_d + (size_t)(s & 1) * 13 * 1024 + blk * 1024
                                  + (w * 16 + fr) * 8) + fq;
      AS4(hbw, pk0);
      AS4(hbw + 256, pk1);
      *(unsigned*)(hout0 + (size_t)t * 800 + u0) = pk0;   // row-major copy for next GEMM
      *(unsigned*)(hout1 + (size_t)t * 800 + u0) = pk1;
    }
    asm volatile("s_waitcnt vmcnt(0)" ::: "memory");   // stores acked at coherence point
    if (lane == 0)
      ASI(flg_d + (s << 6) + blk * 4 + w, 1);
  }
}

// ---------------- tail ----------------
__global__ __launch_bounds__(256) void tail_k(const float* __restrict__ feat,
                                              const float* __restrict__ wo,
                                              float* __restrict__ s_h,
                                              float* __restrict__ s_m)
{
  const int r = blockIdx.x;
  const int tid = threadIdx.x;
  const float* fr = feat + (size_t)r * 1024;
  float sum = 0.f;
  const int n0 = tid * 4;
  #pragma unroll
  for (int j = 0; j < 4; ++j) sum += tanhf_(fr[n0 + j]) * wo[n0 + j];
  #pragma unroll
  for (int off = 32; off > 0; off >>= 1) sum += __shfl_down(sum, off, 64);
  __shared__ float red[4];
  if ((tid & 63) == 0) red[tid >> 6] = sum;
  __syncthreads();
  if (tid == 0)       s_h[r] = red[0] + red[1];
  else if (tid == 64) s_m[r] = red[2] + red[3];
}

__global__ void score_k(const float* __restrict__ s_h, const float* __restrict__ s_m,
                        const float* __restrict__ bo, float* __restrict__ out)
{
  const int bh = blockIdx.x;
  const int m = threadIdx.x;
  out[(size_t)bh * 128 + m] = s_h[bh] + s_m[(bh & ~127) + m] + bo[0];
}

// ---------------- launch ----------------
extern "C" void kernel_launch(void* const* d_in, const int* in_sizes, int n_in,
                              void* d_out, int out_size, void* d_ws, size_t ws_size,
                              hipStream_t stream)
{
  const int*   wt   = (const int*)d_in[0];
  const int*   pt   = (const int*)d_in[2];
  const float* we   = (const float*)d_in[3];
  const float* pe   = (const float*)d_in[4];
  const float* Wih0 = (const float*)d_in[5];
  const float* Whh0 = (const float*)d_in[6];
  const float* b0   = (const float*)d_in[7];
  const float* Wih1 = (const float*)d_in[8];
  const float* Whh1 = (const float*)d_in[9];
  const float* b1   = (const float*)d_in[10];
  const float* Wh   = (const float*)d_in[11];
  const float* bh   = (const float*)d_in[12];
  const float* Wm   = (const float*)d_in[13];
  const float* bm   = (const float*)d_in[14];
  const float* Wo   = (const float*)d_in[15];
  const float* bo   = (const float*)d_in[16];
  float* out = (float*)d_out;

  char* p = (char*)d_ws;
  auto alloc = [&](size_t bytes) { char* q = p; p += (bytes + 255) & ~(size_t)255; return q; };
  f16*   x0    = (f16*)alloc((size_t)4096 * K0P * 2);
  f16*   wihr0 = (f16*)alloc((size_t)GN * K0P * 2);
  f16*   wihr1 = (f16*)alloc((size_t)GN * 800 * 2);
  f16*   whhr0 = (f16*)alloc((size_t)2 * NBLK * 128 * WKP * 2);
  f16*   whhr1 = (f16*)alloc((size_t)2 * NBLK * 128 * WKP * 2);
  f16*   whm   = (f16*)alloc((size_t)1024 * 800 * 2);
  float* biasr0= (float*)alloc(GN * 4);
  float* biasr1= (float*)alloc(GN * 4);
  float* bhm   = (float*)alloc(1024 * 4);
  float* sh    = (float*)alloc(4096 * 4);
  float* sm    = (float*)alloc(4096 * 4);
  f16*   h1    = (f16*)alloc((size_t)4096 * 800 * 2);
  f16*   h2    = (f16*)alloc((size_t)4096 * 800 * 2);
  int*   flg   = (int*)alloc((size_t)2 * 2 * 128 * 64 * 4);  // [layer][d][s][64]
  f16*   hB    = (f16*)alloc(HB_BYTES);
  float* gates = (float*)alloc((size_t)4096 * GN * 4);
  float* feat  = (float*)gates;   // gates dead before feature GEMM

  static bool attr_set = false;
  if (!attr_set) {
    hipFuncSetAttribute((const void*)lstm_mfma_k,
                        hipFuncAttributeMaxDynamicSharedMemorySize, SMEM_LSTM);
    attr_set = true;
  }

  // zero flags + hB (contiguous allocations)
  {
    int zn = (int)(((char*)hB + HB_BYTES - (char*)flg) / 4);
    zero_k<<<512, 256, 0, stream>>>(flg, zn);
  }
  embed_k<<<4096, 128, 0, stream>>>(wt, pt, we, pe, x0);
  wih_reorder_k<<<1024, 256, 0, stream>>>(Wih0, b0, wihr0, biasr0, 400, K0P);
  wih_reorder_k<<<1024, 256, 0, stream>>>(Wih1, b1, wihr1, biasr1, 800, 800);
  whh_reorder_k<<<1024, 256, 0, stream>>>(Whh0, whhr0);
  whh_reorder_k<<<1024, 256, 0, stream>>>(Whh1, whhr1);
  convpad_k<<<1024, 256, 0, stream>>>(Wh, whm, 512, 800, 800);
  convpad_k<<<1024, 256, 0, stream>>>(Wm, whm + (size_t)512 * 800, 512, 800, 800);
  biascat_k<<<1, 1024, 0, stream>>>(bh, bm, bhm);

  // layer 0
  gemm_f16_nt<<<dim3(26, 32), 256, 0, stream>>>(x0, wihr0, biasr0, gates, 4096, GN, K0P);
  lstm_mfma_k<<<26, 256, SMEM_LSTM, stream>>>(gates, whhr0, h1, hB, flg);
  // layer 1
  gemm_f16_nt<<<dim3(26, 32), 256, 0, stream>>>(h1, wihr1, biasr1, gates, 4096, GN, 800);
  lstm_mfma_k<<<26, 256, SMEM_LSTM, stream>>>(gates, whhr1, h2, hB, flg + 2 * 128 * 64);
  // features + scorer
  gemm_f16_nt<<<dim3(8, 32), 256, 0, stream>>>(h2, whm, bhm, feat, 4096, 1024, 800);
  tail_k<<<4096, 256, 0, stream>>>(feat, Wo, sh, sm);
  score_k<<<4096, 128, 0, stream>>>(sh, sm, bo, out);
}

// Round 8
// 1678.924 us; speedup vs baseline: 2.1381x; 1.0542x over previous
//
#include <hip/hip_runtime.h>

#define DEV __device__ __forceinline__

typedef _Float16 f16;
typedef _Float16 f16x8 __attribute__((ext_vector_type(8)));
typedef float f32x4 __attribute__((ext_vector_type(4)));
typedef unsigned long long ull;

static constexpr int K0P  = 416;   // layer0 input dim 400 padded to 13*32
static constexpr int NBLK = 13;    // blocks per direction (13*32 = 416 >= 400 units)
static constexpr int GN   = 3328;  // permuted gate cols = 2*13*128
static constexpr int WKP  = 424;   // padded K for W LDS rows (odd 16B segs -> conflict-free)
static constexpr int SMEM_LSTM = 128 * WKP * 2;              // 108,544 B (W only)
static constexpr int HB1_ELEM  = 2 * 128 * 13 * 1024;        // per-layer hB f16 elems
static constexpr int HB_BYTES  = 2 * HB1_ELEM * 2;           // both layers
static constexpr unsigned READY0 = 0x80008000u;              // -0.0|-0.0 : exact zero, nonzero bits

// ---------------- math helpers ----------------
DEV float sigf(float x) { return 1.f / (1.f + __expf(-x)); }
DEV float tanhf_(float x) {
  x = fminf(10.f, fmaxf(-10.f, x));
  float e = __expf(2.f * x);
  return (e - 1.f) / (e + 1.f);
}
DEV ull  AL8(const ull* p) { return __hip_atomic_load(p, __ATOMIC_RELAXED, __HIP_MEMORY_SCOPE_AGENT); }
DEV void AS4(unsigned* p, unsigned v) { __hip_atomic_store(p, v, __ATOMIC_RELAXED, __HIP_MEMORY_SCOPE_AGENT); }

// row permutation: loc in [0,128): w=loc>>5, t=(loc>>4)&1, fq=(loc>>2)&3, g=loc&3
// unit u = blk*32 + w*8 + 2*fq + t ; gate g (i,f,g,o)

// ---------------- embedding gather -> x0 f16 [4096][416] ----------------
__global__ void embed_k(const int* __restrict__ wt, const int* __restrict__ pt,
                        const float* __restrict__ we, const float* __restrict__ pe,
                        f16* __restrict__ x0)
{
  const int r = blockIdx.x;
  const int tid = threadIdx.x;
  const int w = wt[r], p = pt[r];
  const float* wrow = we + (size_t)w * 300;
  const float* prow = pe + (size_t)p * 100;
  f16* xr = x0 + (size_t)r * K0P;
  for (int k = tid; k < K0P; k += 128) {
    float v = (k < 300) ? wrow[k] : (k < 400 ? prow[k - 300] : 0.f);
    xr[k] = (f16)v;
  }
}

// ---------------- f32 -> f16 with optional K padding ----------------
__global__ void convpad_k(const float* __restrict__ src, f16* __restrict__ dst,
                          int rows, int K, int KP)
{
  const size_t total = (size_t)rows * KP;
  for (size_t i = (size_t)blockIdx.x * blockDim.x + threadIdx.x; i < total;
       i += (size_t)gridDim.x * blockDim.x) {
    int r = (int)(i / KP), k = (int)(i % KP);
    dst[i] = (f16)(k < K ? src[(size_t)r * K + k] : 0.f);
  }
}

// Wih f32 [2][1600][K] + bias -> permuted f16 [GN][KP] + biasr [GN]
__global__ void wih_reorder_k(const float* __restrict__ src, const float* __restrict__ bias,
                              f16* __restrict__ dst, float* __restrict__ biasr,
                              int K, int KP)
{
  const size_t total = (size_t)GN * KP;
  for (size_t i = (size_t)blockIdx.x * blockDim.x + threadIdx.x; i < total;
       i += (size_t)gridDim.x * blockDim.x) {
    int k = (int)(i % KP);
    int R = (int)(i / KP);
    int d = R / 1664, rr = R % 1664, blk = rr >> 7, loc = rr & 127;
    int w = loc >> 5, t = (loc >> 4) & 1, fq = (loc >> 2) & 3, g = loc & 3;
    int u = blk * 32 + w * 8 + 2 * fq + t;
    float v = (u < 400 && k < K) ? src[((size_t)d * 1600 + g * 400 + u) * K + k] : 0.f;
    dst[i] = (f16)v;
    if (k == 0) biasr[R] = (u < 400) ? bias[d * 1600 + g * 400 + u] : 0.f;
  }
}

// Whh f32 [2][1600][400] -> reordered f16 [2][NBLK][128][WKP]
__global__ void whh_reorder_k(const float* __restrict__ src, f16* __restrict__ dst)
{
  const int total = 2 * NBLK * 128 * WKP;
  for (int i = blockIdx.x * blockDim.x + threadIdx.x; i < total;
       i += gridDim.x * blockDim.x) {
    int k = i % WKP, loc = (i / WKP) & 127, blk = (i / (WKP * 128)) % NBLK,
        d = i / (WKP * 128 * NBLK);
    int w = loc >> 5, t = (loc >> 4) & 1, fq = (loc >> 2) & 3, g = loc & 3;
    int u = blk * 32 + w * 8 + 2 * fq + t;
    float v = (u < 400 && k < 400) ? src[((size_t)d * 1600 + g * 400 + u) * 400 + k] : 0.f;
    dst[i] = (f16)v;
  }
}

__global__ void biascat_k(const float* __restrict__ bh, const float* __restrict__ bm,
                          float* __restrict__ bhm)
{
  int i = threadIdx.x;
  bhm[i] = i < 512 ? bh[i] : bm[i - 512];
}

// hB init: zero real slots, READY0 in pad slots (block 12, dword ranges
// [128,256) and [384,512) within each (d,s) slab = units 400..415, never written).
__global__ void init_hb_k(unsigned* __restrict__ p, int n)
{
  for (int i = blockIdx.x * blockDim.x + threadIdx.x; i < n; i += gridDim.x * blockDim.x) {
    int off = i % (13 * 512);
    int blk = off >> 9, win = off & 511;
    bool pad = (blk == 12) && ((win >> 7) & 1);
    p[i] = pad ? READY0 : 0u;
  }
}

// ---------------- GEMM: C[M][N] = A[M][KP] * B[N][KP]^T + bias[n] ----------------
__global__ __launch_bounds__(256) void gemm_f16_nt(
    const f16* __restrict__ A, const f16* __restrict__ Bw,
    const float* __restrict__ bias, float* __restrict__ C,
    int M, int N, int KP)
{
  __shared__ __align__(16) f16 As[128][40];
  __shared__ __align__(16) f16 Bs[128][40];
  const int tid = threadIdx.x;
  const int bn = blockIdx.x, bm = blockIdx.y;
  const int lane = tid & 63, wid = tid >> 6;
  const int wr = wid >> 1, wc = wid & 1;
  const int srow = tid >> 1, shalf = tid & 1;
  const f16* Ap = A + (size_t)(bm * 128 + srow) * KP + shalf * 16;
  const f16* Bp = Bw + (size_t)(bn * 128 + srow) * KP + shalf * 16;
  const int fr = lane & 15, fq = lane >> 4;
  f32x4 acc[4][4] = {};
  for (int kt = 0; kt < KP; kt += 32) {
    __syncthreads();
    *(uint4*)&As[srow][shalf * 16]     = *(const uint4*)(Ap + kt);
    *(uint4*)&As[srow][shalf * 16 + 8] = *(const uint4*)(Ap + kt + 8);
    *(uint4*)&Bs[srow][shalf * 16]     = *(const uint4*)(Bp + kt);
    *(uint4*)&Bs[srow][shalf * 16 + 8] = *(const uint4*)(Bp + kt + 8);
    __syncthreads();
    f16x8 af[4], bf[4];
    #pragma unroll
    for (int m = 0; m < 4; ++m) af[m] = *(const f16x8*)&As[wr * 64 + m * 16 + fr][fq * 8];
    #pragma unroll
    for (int n = 0; n < 4; ++n) bf[n] = *(const f16x8*)&Bs[wc * 64 + n * 16 + fr][fq * 8];
    #pragma unroll
    for (int m = 0; m < 4; ++m)
      #pragma unroll
      for (int n = 0; n < 4; ++n)
        acc[m][n] = __builtin_amdgcn_mfma_f32_16x16x32_f16(af[m], bf[n], acc[m][n], 0, 0, 0);
  }
  #pragma unroll
  for (int n = 0; n < 4; ++n) {
    const int gn = bn * 128 + wc * 64 + n * 16 + fr;
    const float bv = bias ? bias[gn] : 0.f;
    #pragma unroll
    for (int m = 0; m < 4; ++m) {
      const size_t gm = (size_t)bm * 128 + wr * 64 + m * 16 + fq * 4;
      #pragma unroll
      for (int r = 0; r < 4; ++r)
        C[(gm + r) * (size_t)N + gn] = acc[m][n][r] + bv;
    }
  }
}

// ---------------- recurrence: 26 blocks, pure data-flow handoff ----------------
// hB [d][s][blk][1024] f16. Real slots zero-init; pad slots READY0-init. A packed
// h-dword is its own ready flag: producers substitute READY0 for an all-zero pair.
__global__ __launch_bounds__(256) void lstm_mfma_k(
    const float* __restrict__ gates,
    const f16* __restrict__ whh_r,
    f16* __restrict__ h_out,
    f16* __restrict__ hB)
{
  extern __shared__ __align__(16) char smem[];
  f16* W_lds = (f16*)smem;                 // [128][WKP]

  const int d = blockIdx.x / NBLK, blk = blockIdx.x % NBLK;
  const int tid = threadIdx.x;
  const int lane = tid & 63, w = tid >> 6;
  const int fr = lane & 15, fq = lane >> 4;

  // W slice -> LDS once
  {
    const uint4* src = (const uint4*)(whh_r + ((size_t)d * NBLK + blk) * 128 * WKP);
    uint4* dst = (uint4*)W_lds;
    for (int i = tid; i < 128 * WKP / 8; i += 256) dst[i] = src[i];
  }
  __syncthreads();   // the only barrier in this kernel

  // per-lane constants
  const int u0 = blk * 32 + w * 8 + 2 * fq;   // even; u1 = u0+1
  const bool ok = u0 < 400;
  const float* gbase0 = gates + (size_t)(fr * 128) * GN + d * 1664 + blk * 128 + w * 32;
  const float* gbase1 = gbase0 + (size_t)16 * 128 * GN;
  f16* hout0 = h_out + (size_t)(fr * 128) * 800 + d * 400;
  f16* hout1 = hout0 + (size_t)16 * 128 * 800;
  const f16* a0base = W_lds + (size_t)(w * 32 + fr) * WKP + fq * 8;
  const f16* a1base = a0base + 16 * WKP;
  f16* hb_d = hB + (size_t)d * 128 * 13 * 1024;

  float c00 = 0.f, c01 = 0.f, c10 = 0.f, c11 = 0.f;

  for (int s = 0; s < 128; ++s) {
    const int t = d ? 127 - s : s;
    // gate prefetch (plain cached loads; i,f,g,o packed per unit)
    const float* g0 = gbase0 + (size_t)t * GN;
    const float* g1 = gbase1 + (size_t)t * GN;
    float4 p00 = *(const float4*)(g0 + fq * 4);
    float4 p10 = *(const float4*)(g0 + 16 + fq * 4);
    float4 p01 = *(const float4*)(g1 + fq * 4);
    float4 p11 = *(const float4*)(g1 + 16 + fq * 4);

    f32x4 acc00 = {}, acc01 = {}, acc10 = {}, acc11 = {};
    if (s > 0) {
      // data-flow poll: issue ALL outstanding loads back-to-back, then check;
      // re-issue only failures. Forces the whole fragment set in flight at once.
      const ull* hbq = (const ull*)(hb_d + (size_t)(s - 1) * 13 * 1024) + lane * 2;
      ull q[13][4];
      ull mask = ~0ull;
      for (;;) {
        #pragma unroll
        for (int kk = 0; kk < 13; ++kk) {
          const ull* pp = hbq + kk * 256;
          if ((mask >> (kk * 4 + 0)) & 1) q[kk][0] = AL8(pp);
          if ((mask >> (kk * 4 + 1)) & 1) q[kk][1] = AL8(pp + 1);
          if ((mask >> (kk * 4 + 2)) & 1) q[kk][2] = AL8(pp + 128);
          if ((mask >> (kk * 4 + 3)) & 1) q[kk][3] = AL8(pp + 129);
        }
        __builtin_amdgcn_sched_barrier(0);   // keep all loads issued before checks
        ull nm = 0;
        #pragma unroll
        for (int kk = 0; kk < 13; ++kk)
          #pragma unroll
          for (int j = 0; j < 4; ++j) {
            ull v = q[kk][j];
            if ((unsigned)v == 0u || (unsigned)(v >> 32) == 0u)
              nm |= 1ull << (kk * 4 + j);
          }
        mask = nm;
        if (!__any(nm != 0ull)) break;
        __builtin_amdgcn_s_sleep(1);
      }
      #pragma unroll
      for (int kk = 0; kk < 13; ++kk) {
        f16x8 a0 = *(const f16x8*)(a0base + kk * 32);
        f16x8 a1 = *(const f16x8*)(a1base + kk * 32);
        union { ull u[2]; f16x8 v; } B0, B1;
        B0.u[0] = q[kk][0]; B0.u[1] = q[kk][1];
        B1.u[0] = q[kk][2]; B1.u[1] = q[kk][3];
        acc00 = __builtin_amdgcn_mfma_f32_16x16x32_f16(a0, B0.v, acc00, 0, 0, 0);
        acc01 = __builtin_amdgcn_mfma_f32_16x16x32_f16(a0, B1.v, acc01, 0, 0, 0);
        acc10 = __builtin_amdgcn_mfma_f32_16x16x32_f16(a1, B0.v, acc10, 0, 0, 0);
        acc11 = __builtin_amdgcn_mfma_f32_16x16x32_f16(a1, B1.v, acc11, 0, 0, 0);
      }
    }

    // in-register activations: acc reg r = gate r (i,f,g,o) of one unit
    auto act = [&](const f32x4& a, const float4& p, float& c) -> f16 {
      float vi = a[0] + p.x, vf = a[1] + p.y, vg = a[2] + p.z, vo = a[3] + p.w;
      c = sigf(vf) * c + sigf(vi) * tanhf_(vg);
      return (f16)(sigf(vo) * tanhf_(c));
    };
    f16 h00 = act(acc00, p00, c00);   // (u0,   batch fr)
    f16 h10 = act(acc10, p10, c10);   // (u0+1, batch fr)
    f16 h01 = act(acc01, p01, c01);   // (u0,   batch fr+16)
    f16 h11 = act(acc11, p11, c11);   // (u0+1, batch fr+16)

    if (ok) {
      unsigned pk0 = (unsigned)__builtin_bit_cast(unsigned short, h00) |
                     ((unsigned)__builtin_bit_cast(unsigned short, h10) << 16);
      unsigned pk1 = (unsigned)__builtin_bit_cast(unsigned short, h01) |
                     ((unsigned)__builtin_bit_cast(unsigned short, h11) << 16);
      if (pk0 == 0u) pk0 = READY0;   // -0|-0: numerically exact zero, nonzero bits
      if (pk1 == 0u) pk1 = READY0;
      unsigned* hbw = (unsigned*)(hb_d + (size_t)s * 13 * 1024 + blk * 1024
                                  + (w * 16 + fr) * 8) + fq;
      AS4(hbw, pk0);          // publish: store flight is the only handoff latency
      AS4(hbw + 256, pk1);
      *(unsigned*)(hout0 + (size_t)t * 800 + u0) = pk0;   // row-major for next GEMM
      *(unsigned*)(hout1 + (size_t)t * 800 + u0) = pk1;
    }
  }
}

// ---------------- tail ----------------
__global__ __launch_bounds__(256) void tail_k(const float* __restrict__ feat,
                                              const float* __restrict__ wo,
                                              float* __restrict__ s_h,
                                              float* __restrict__ s_m)
{
  const int r = blockIdx.x;
  const int tid = threadIdx.x;
  const float* fr = feat + (size_t)r * 1024;
  float sum = 0.f;
  const int n0 = tid * 4;
  #pragma unroll
  for (int j = 0; j < 4; ++j) sum += tanhf_(fr[n0 + j]) * wo[n0 + j];
  #pragma unroll
  for (int off = 32; off > 0; off >>= 1) sum += __shfl_down(sum, off, 64);
  __shared__ float red[4];
  if ((tid & 63) == 0) red[tid >> 6] = sum;
  __syncthreads();
  if (tid == 0)       s_h[r] = red[0] + red[1];
  else if (tid == 64) s_m[r] = red[2] + red[3];
}

__global__ void score_k(const float* __restrict__ s_h, const float* __restrict__ s_m,
                        const float* __restrict__ bo, float* __restrict__ out)
{
  const int bh = blockIdx.x;
  const int m = threadIdx.x;
  out[(size_t)bh * 128 + m] = s_h[bh] + s_m[(bh & ~127) + m] + bo[0];
}

// ---------------- launch ----------------
extern "C" void kernel_launch(void* const* d_in, const int* in_sizes, int n_in,
                              void* d_out, int out_size, void* d_ws, size_t ws_size,
                              hipStream_t stream)
{
  const int*   wt   = (const int*)d_in[0];
  const int*   pt   = (const int*)d_in[2];
  const float* we   = (const float*)d_in[3];
  const float* pe   = (const float*)d_in[4];
  const float* Wih0 = (const float*)d_in[5];
  const float* Whh0 = (const float*)d_in[6];
  const float* b0   = (const float*)d_in[7];
  const float* Wih1 = (const float*)d_in[8];
  const float* Whh1 = (const float*)d_in[9];
  const float* b1   = (const float*)d_in[10];
  const float* Wh   = (const float*)d_in[11];
  const float* bh   = (const float*)d_in[12];
  const float* Wm   = (const float*)d_in[13];
  const float* bm   = (const float*)d_in[14];
  const float* Wo   = (const float*)d_in[15];
  const float* bo   = (const float*)d_in[16];
  float* out = (float*)d_out;

  char* p = (char*)d_ws;
  auto alloc = [&](size_t bytes) { char* q = p; p += (bytes + 255) & ~(size_t)255; return q; };
  f16*   x0    = (f16*)alloc((size_t)4096 * K0P * 2);
  f16*   wihr0 = (f16*)alloc((size_t)GN * K0P * 2);
  f16*   wihr1 = (f16*)alloc((size_t)GN * 800 * 2);
  f16*   whhr0 = (f16*)alloc((size_t)2 * NBLK * 128 * WKP * 2);
  f16*   whhr1 = (f16*)alloc((size_t)2 * NBLK * 128 * WKP * 2);
  f16*   whm   = (f16*)alloc((size_t)1024 * 800 * 2);
  float* biasr0= (float*)alloc(GN * 4);
  float* biasr1= (float*)alloc(GN * 4);
  float* bhm   = (float*)alloc(1024 * 4);
  float* sh    = (float*)alloc(4096 * 4);
  float* sm    = (float*)alloc(4096 * 4);
  f16*   h1    = (f16*)alloc((size_t)4096 * 800 * 2);
  f16*   h2    = (f16*)alloc((size_t)4096 * 800 * 2);
  f16*   hB    = (f16*)alloc(HB_BYTES);          // [layer][d][s][blk][1024]
  float* gates = (float*)alloc((size_t)4096 * GN * 4);
  float* feat  = (float*)gates;   // gates dead before feature GEMM

  static bool attr_set = false;
  if (!attr_set) {
    hipFuncSetAttribute((const void*)lstm_mfma_k,
                        hipFuncAttributeMaxDynamicSharedMemorySize, SMEM_LSTM);
    attr_set = true;
  }

  // hB: zero real slots, READY0 only in never-written pad slots
  init_hb_k<<<512, 256, 0, stream>>>((unsigned*)hB, HB_BYTES / 4);
  embed_k<<<4096, 128, 0, stream>>>(wt, pt, we, pe, x0);
  wih_reorder_k<<<1024, 256, 0, stream>>>(Wih0, b0, wihr0, biasr0, 400, K0P);
  wih_reorder_k<<<1024, 256, 0, stream>>>(Wih1, b1, wihr1, biasr1, 800, 800);
  whh_reorder_k<<<1024, 256, 0, stream>>>(Whh0, whhr0);
  whh_reorder_k<<<1024, 256, 0, stream>>>(Whh1, whhr1);
  convpad_k<<<1024, 256, 0, stream>>>(Wh, whm, 512, 800, 800);
  convpad_k<<<1024, 256, 0, stream>>>(Wm, whm + (size_t)512 * 800, 512, 800, 800);
  biascat_k<<<1, 1024, 0, stream>>>(bh, bm, bhm);

  // layer 0
  gemm_f16_nt<<<dim3(26, 32), 256, 0, stream>>>(x0, wihr0, biasr0, gates, 4096, GN, K0P);
  lstm_mfma_k<<<26, 256, SMEM_LSTM, stream>>>(gates, whhr0, h1, hB);
  // layer 1
  gemm_f16_nt<<<dim3(26, 32), 256, 0, stream>>>(h1, wihr1, biasr1, gates, 4096, GN, 800);
  lstm_mfma_k<<<26, 256, SMEM_LSTM, stream>>>(gates, whhr1, h2, hB + HB1_ELEM);
  // features + scorer
  gemm_f16_nt<<<dim3(8, 32), 256, 0, stream>>>(h2, whm, bhm, feat, 4096, 1024, 800);
  tail_k<<<4096, 256, 0, stream>>>(feat, Wo, sh, sm);
  score_k<<<4096, 128, 0, stream>>>(sh, sm, bo, out);
}

// Round 9
// 1365.890 us; speedup vs baseline: 2.6281x; 1.2292x over previous
//
#include <hip/hip_runtime.h>

#define DEV __device__ __forceinline__

typedef _Float16 f16;
typedef _Float16 f16x8 __attribute__((ext_vector_type(8)));
typedef float f32x4 __attribute__((ext_vector_type(4)));
typedef unsigned long long ull;

static constexpr int K0P  = 416;   // layer0 input dim 400 padded to 13*32
static constexpr int NBLK = 13;    // blocks per direction (13*32 = 416 >= 400 units)
static constexpr int GN   = 3328;  // permuted gate cols = 2*13*128
static constexpr int WKP  = 424;   // padded K for W LDS rows (odd 16B segs -> conflict-free)
static constexpr int HX_OFF = 128 * WKP * 2;                 // 108,544 B (W)
static constexpr int FL_OFF = HX_OFF + 13 * 2560;            // hx: [13][64 lanes][4 qw], 40B/lane
static constexpr int SMEM_LSTM = FL_OFF + 16;                // 141,840 B
static constexpr int HB1_ELEM  = 2 * 128 * 13 * 1024;        // per-layer hB f16 elems
static constexpr int HB_BYTES  = 2 * HB1_ELEM * 2;           // both layers
static constexpr unsigned READY0 = 0x80008000u;              // -0.0|-0.0 : exact zero, nonzero bits

// ---------------- math helpers ----------------
DEV float sigf(float x) { return 1.f / (1.f + __expf(-x)); }
DEV float tanhf_(float x) {
  x = fminf(10.f, fmaxf(-10.f, x));
  float e = __expf(2.f * x);
  return (e - 1.f) / (e + 1.f);
}
DEV ull  AL8(const ull* p) { return __hip_atomic_load(p, __ATOMIC_RELAXED, __HIP_MEMORY_SCOPE_AGENT); }
DEV void AS4(unsigned* p, unsigned v) { __hip_atomic_store(p, v, __ATOMIC_RELAXED, __HIP_MEMORY_SCOPE_AGENT); }

// row permutation: loc in [0,128): w=loc>>5, t=(loc>>4)&1, fq=(loc>>2)&3, g=loc&3
// unit u = blk*32 + w*8 + 2*fq + t ; gate g (i,f,g,o)

// ---------------- embedding gather -> x0 f16 [4096][416] ----------------
__global__ void embed_k(const int* __restrict__ wt, const int* __restrict__ pt,
                        const float* __restrict__ we, const float* __restrict__ pe,
                        f16* __restrict__ x0)
{
  const int r = blockIdx.x;
  const int tid = threadIdx.x;
  const int w = wt[r], p = pt[r];
  const float* wrow = we + (size_t)w * 300;
  const float* prow = pe + (size_t)p * 100;
  f16* xr = x0 + (size_t)r * K0P;
  for (int k = tid; k < K0P; k += 128) {
    float v = (k < 300) ? wrow[k] : (k < 400 ? prow[k - 300] : 0.f);
    xr[k] = (f16)v;
  }
}

// ---------------- f32 -> f16 with optional K padding ----------------
__global__ void convpad_k(const float* __restrict__ src, f16* __restrict__ dst,
                          int rows, int K, int KP)
{
  const size_t total = (size_t)rows * KP;
  for (size_t i = (size_t)blockIdx.x * blockDim.x + threadIdx.x; i < total;
       i += (size_t)gridDim.x * blockDim.x) {
    int r = (int)(i / KP), k = (int)(i % KP);
    dst[i] = (f16)(k < K ? src[(size_t)r * K + k] : 0.f);
  }
}

// Wih f32 [2][1600][K] + bias -> permuted f16 [GN][KP] + biasr [GN]
__global__ void wih_reorder_k(const float* __restrict__ src, const float* __restrict__ bias,
                              f16* __restrict__ dst, float* __restrict__ biasr,
                              int K, int KP)
{
  const size_t total = (size_t)GN * KP;
  for (size_t i = (size_t)blockIdx.x * blockDim.x + threadIdx.x; i < total;
       i += (size_t)gridDim.x * blockDim.x) {
    int k = (int)(i % KP);
    int R = (int)(i / KP);
    int d = R / 1664, rr = R % 1664, blk = rr >> 7, loc = rr & 127;
    int w = loc >> 5, t = (loc >> 4) & 1, fq = (loc >> 2) & 3, g = loc & 3;
    int u = blk * 32 + w * 8 + 2 * fq + t;
    float v = (u < 400 && k < K) ? src[((size_t)d * 1600 + g * 400 + u) * K + k] : 0.f;
    dst[i] = (f16)v;
    if (k == 0) biasr[R] = (u < 400) ? bias[d * 1600 + g * 400 + u] : 0.f;
  }
}

// Whh f32 [2][1600][400] -> reordered f16 [2][NBLK][128][WKP]
__global__ void whh_reorder_k(const float* __restrict__ src, f16* __restrict__ dst)
{
  const int total = 2 * NBLK * 128 * WKP;
  for (int i = blockIdx.x * blockDim.x + threadIdx.x; i < total;
       i += gridDim.x * blockDim.x) {
    int k = i % WKP, loc = (i / WKP) & 127, blk = (i / (WKP * 128)) % NBLK,
        d = i / (WKP * 128 * NBLK);
    int w = loc >> 5, t = (loc >> 4) & 1, fq = (loc >> 2) & 3, g = loc & 3;
    int u = blk * 32 + w * 8 + 2 * fq + t;
    float v = (u < 400 && k < 400) ? src[((size_t)d * 1600 + g * 400 + u) * 400 + k] : 0.f;
    dst[i] = (f16)v;
  }
}

__global__ void biascat_k(const float* __restrict__ bh, const float* __restrict__ bm,
                          float* __restrict__ bhm)
{
  int i = threadIdx.x;
  bhm[i] = i < 512 ? bh[i] : bm[i - 512];
}

// hB init: zero real slots, READY0 in pad slots (block 12, dword ranges
// [128,256) and [384,512) within each (d,s) slab = units 400..415, never written).
__global__ void init_hb_k(unsigned* __restrict__ p, int n)
{
  for (int i = blockIdx.x * blockDim.x + threadIdx.x; i < n; i += gridDim.x * blockDim.x) {
    int off = i % (13 * 512);
    int blk = off >> 9, win = off & 511;
    bool pad = (blk == 12) && ((win >> 7) & 1);
    p[i] = pad ? READY0 : 0u;
  }
}

// ---------------- GEMM: C[M][N] = A[M][KP] * B[N][KP]^T + bias[n] ----------------
__global__ __launch_bounds__(256) void gemm_f16_nt(
    const f16* __restrict__ A, const f16* __restrict__ Bw,
    const float* __restrict__ bias, float* __restrict__ C,
    int M, int N, int KP)
{
  __shared__ __align__(16) f16 As[128][40];
  __shared__ __align__(16) f16 Bs[128][40];
  const int tid = threadIdx.x;
  const int bn = blockIdx.x, bm = blockIdx.y;
  const int lane = tid & 63, wid = tid >> 6;
  const int wr = wid >> 1, wc = wid & 1;
  const int srow = tid >> 1, shalf = tid & 1;
  const f16* Ap = A + (size_t)(bm * 128 + srow) * KP + shalf * 16;
  const f16* Bp = Bw + (size_t)(bn * 128 + srow) * KP + shalf * 16;
  const int fr = lane & 15, fq = lane >> 4;
  f32x4 acc[4][4] = {};
  for (int kt = 0; kt < KP; kt += 32) {
    __syncthreads();
    *(uint4*)&As[srow][shalf * 16]     = *(const uint4*)(Ap + kt);
    *(uint4*)&As[srow][shalf * 16 + 8] = *(const uint4*)(Ap + kt + 8);
    *(uint4*)&Bs[srow][shalf * 16]     = *(const uint4*)(Bp + kt);
    *(uint4*)&Bs[srow][shalf * 16 + 8] = *(const uint4*)(Bp + kt + 8);
    __syncthreads();
    f16x8 af[4], bf[4];
    #pragma unroll
    for (int m = 0; m < 4; ++m) af[m] = *(const f16x8*)&As[wr * 64 + m * 16 + fr][fq * 8];
    #pragma unroll
    for (int n = 0; n < 4; ++n) bf[n] = *(const f16x8*)&Bs[wc * 64 + n * 16 + fr][fq * 8];
    #pragma unroll
    for (int m = 0; m < 4; ++m)
      #pragma unroll
      for (int n = 0; n < 4; ++n)
        acc[m][n] = __builtin_amdgcn_mfma_f32_16x16x32_f16(af[m], bf[n], acc[m][n], 0, 0, 0);
  }
  #pragma unroll
  for (int n = 0; n < 4; ++n) {
    const int gn = bn * 128 + wc * 64 + n * 16 + fr;
    const float bv = bias ? bias[gn] : 0.f;
    #pragma unroll
    for (int m = 0; m < 4; ++m) {
      const size_t gm = (size_t)bm * 128 + wr * 64 + m * 16 + fq * 4;
      #pragma unroll
      for (int r = 0; r < 4; ++r)
        C[(gm + r) * (size_t)N + gn] = acc[m][n][r] + bv;
    }
  }
}

// ---------------- recurrence: 26 blocks, wave-partitioned poll + LDS share ------
// hB [d][s][blk][1024] f16 (pad slots READY0). Wave w polls only its kk-subset
// ({4,3,3,3} of 13), stages ready qwords into LDS hx, sets per-kk flag bit;
// all waves spin on the LDS flag word and feed MFMA B-fragments from LDS.
__global__ __launch_bounds__(256) void lstm_mfma_k(
    const float* __restrict__ gates,
    const f16* __restrict__ whh_r,
    f16* __restrict__ h_out,
    f16* __restrict__ hB)
{
  extern __shared__ __align__(16) char smem[];
  f16*  W_lds = (f16*)smem;                 // [128][WKP]
  char* hx    = smem + HX_OFF;              // [13][64][4 qw], 40B lane stride
  int*  flags = (int*)(smem + FL_OFF);      // [2] parity words

  const int d = blockIdx.x / NBLK, blk = blockIdx.x % NBLK;
  const int tid = threadIdx.x;
  const int lane = tid & 63, w = tid >> 6;
  const int fr = lane & 15, fq = lane >> 4;

  // W slice -> LDS once
  {
    const uint4* src = (const uint4*)(whh_r + ((size_t)d * NBLK + blk) * 128 * WKP);
    uint4* dst = (uint4*)W_lds;
    for (int i = tid; i < 128 * WKP / 8; i += 256) dst[i] = src[i];
  }
  if (tid < 2) flags[tid] = 0;
  __syncthreads();

  // per-lane constants
  const int u0 = blk * 32 + w * 8 + 2 * fq;   // even; u1 = u0+1
  const bool ok = u0 < 400;
  const float* gbase0 = gates + (size_t)(fr * 128) * GN + d * 1664 + blk * 128 + w * 32;
  const float* gbase1 = gbase0 + (size_t)16 * 128 * GN;
  f16* hout0 = h_out + (size_t)(fr * 128) * 800 + d * 400;
  f16* hout1 = hout0 + (size_t)16 * 128 * 800;
  const f16* a0base = W_lds + (size_t)(w * 32 + fr) * WKP + fq * 8;
  const f16* a1base = a0base + 16 * WKP;
  f16* hb_d = hB + (size_t)d * 128 * 13 * 1024;

  const int nkk = (w == 0) ? 4 : 3;           // poll partition {4,3,3,3}
  const int kk0 = (w == 0) ? 0 : 4 + 3 * (w - 1);

  float c00 = 0.f, c01 = 0.f, c10 = 0.f, c11 = 0.f;

  for (int s = 0; s < 128; ++s) {
    const int t = d ? 127 - s : s;
    f32x4 acc00 = {}, acc01 = {}, acc10 = {}, acc11 = {};
    float4 p00, p10, p01, p11;

    if (s > 0) {
      // ---- L3 poll of my kk subset only ----
      const ull* slab = (const ull*)(hb_d + (size_t)(s - 1) * 13 * 1024) + lane * 2;
      ull q[4][4];
      const unsigned full = (1u << nkk) - 1;
      unsigned pend = (nkk == 4) ? 0xFFFFu : 0x0FFFu;
      unsigned wrote = 0, flagged = 0;
      int* fw = &flags[s & 1];
      while (flagged != full) {
        #pragma unroll
        for (int i = 0; i < 4; ++i)
          if (i < nkk) {
            const ull* pp = slab + (kk0 + i) * 256;
            if ((pend >> (i * 4 + 0)) & 1) q[i][0] = AL8(pp);
            if ((pend >> (i * 4 + 1)) & 1) q[i][1] = AL8(pp + 1);
            if ((pend >> (i * 4 + 2)) & 1) q[i][2] = AL8(pp + 128);
            if ((pend >> (i * 4 + 3)) & 1) q[i][3] = AL8(pp + 129);
          }
        __builtin_amdgcn_sched_barrier(0);   // keep loads issued before checks
        #pragma unroll
        for (int i = 0; i < 4; ++i)
          if (i < nkk)
            #pragma unroll
            for (int j = 0; j < 4; ++j)
              if ((pend >> (i * 4 + j)) & 1) {
                ull v = q[i][j];
                if ((unsigned)v != 0u && (unsigned)(v >> 32) != 0u)
                  pend &= ~(1u << (i * 4 + j));
              }
        // stage completed kks into LDS
        #pragma unroll
        for (int i = 0; i < 4; ++i)
          if (i < nkk && !((wrote >> i) & 1) && ((pend >> (i * 4)) & 15u) == 0u) {
            char* hp = hx + (kk0 + i) * 2560 + lane * 40;
            *(ull*)(hp +  0) = q[i][0];
            *(ull*)(hp +  8) = q[i][1];
            *(ull*)(hp + 16) = q[i][2];
            *(ull*)(hp + 24) = q[i][3];
            wrote |= 1u << i;
          }
        // publish per-kk flags once the whole wave's slice is staged
        #pragma unroll
        for (int i = 0; i < 4; ++i)
          if (i < nkk && !((flagged >> i) & 1)) {
            bool done = ((pend >> (i * 4)) & 15u) == 0u;
            if (__all(done)) {
              asm volatile("s_waitcnt lgkmcnt(0)" ::: "memory");
              if (lane == 0)
                __hip_atomic_fetch_or(fw, 1 << (kk0 + i), __ATOMIC_RELAXED,
                                      __HIP_MEMORY_SCOPE_WORKGROUP);
              flagged |= 1u << i;
            }
          }
        if (flagged != full) __builtin_amdgcn_s_sleep(2);
      }
      // gate prefetch: flies under the LDS spin + MFMA
      const float* g0 = gbase0 + (size_t)t * GN;
      const float* g1 = gbase1 + (size_t)t * GN;
      p00 = *(const float4*)(g0 + fq * 4);
      p10 = *(const float4*)(g0 + 16 + fq * 4);
      p01 = *(const float4*)(g1 + fq * 4);
      p11 = *(const float4*)(g1 + 16 + fq * 4);
      // wait for all 13 kk staged (intra-CU spin, acquire)
      while ((__hip_atomic_load(fw, __ATOMIC_ACQUIRE, __HIP_MEMORY_SCOPE_WORKGROUP)
              & 0x1FFF) != 0x1FFF)
        __builtin_amdgcn_s_sleep(1);
      __builtin_amdgcn_sched_barrier(0);
      // MFMA with B-fragments from LDS
      #pragma unroll
      for (int kk = 0; kk < 13; ++kk) {
        const char* hp = hx + kk * 2560 + lane * 40;
        f16x8 a0 = *(const f16x8*)(a0base + kk * 32);
        f16x8 a1 = *(const f16x8*)(a1base + kk * 32);
        union { ull u[2]; f16x8 v; } B0, B1;
        B0.u[0] = *(const ull*)(hp);      B0.u[1] = *(const ull*)(hp + 8);
        B1.u[0] = *(const ull*)(hp + 16); B1.u[1] = *(const ull*)(hp + 24);
        acc00 = __builtin_amdgcn_mfma_f32_16x16x32_f16(a0, B0.v, acc00, 0, 0, 0);
        acc01 = __builtin_amdgcn_mfma_f32_16x16x32_f16(a0, B1.v, acc01, 0, 0, 0);
        acc10 = __builtin_amdgcn_mfma_f32_16x16x32_f16(a1, B0.v, acc10, 0, 0, 0);
        acc11 = __builtin_amdgcn_mfma_f32_16x16x32_f16(a1, B1.v, acc11, 0, 0, 0);
      }
    } else {
      const float* g0 = gbase0 + (size_t)t * GN;
      const float* g1 = gbase1 + (size_t)t * GN;
      p00 = *(const float4*)(g0 + fq * 4);
      p10 = *(const float4*)(g0 + 16 + fq * 4);
      p01 = *(const float4*)(g1 + fq * 4);
      p11 = *(const float4*)(g1 + 16 + fq * 4);
    }

    __syncthreads();                       // all hx reads done; safe to reuse next step
    if (tid == 0)
      __hip_atomic_store(&flags[s & 1], 0, __ATOMIC_RELAXED, __HIP_MEMORY_SCOPE_WORKGROUP);

    // in-register activations: acc reg r = gate r (i,f,g,o) of one unit
    auto act = [&](const f32x4& a, const float4& p, float& c) -> f16 {
      float vi = a[0] + p.x, vf = a[1] + p.y, vg = a[2] + p.z, vo = a[3] + p.w;
      c = sigf(vf) * c + sigf(vi) * tanhf_(vg);
      return (f16)(sigf(vo) * tanhf_(c));
    };
    f16 h00 = act(acc00, p00, c00);   // (u0,   batch fr)
    f16 h10 = act(acc10, p10, c10);   // (u0+1, batch fr)
    f16 h01 = act(acc01, p01, c01);   // (u0,   batch fr+16)
    f16 h11 = act(acc11, p11, c11);   // (u0+1, batch fr+16)

    if (ok) {
      unsigned pk0 = (unsigned)__builtin_bit_cast(unsigned short, h00) |
                     ((unsigned)__builtin_bit_cast(unsigned short, h10) << 16);
      unsigned pk1 = (unsigned)__builtin_bit_cast(unsigned short, h01) |
                     ((unsigned)__builtin_bit_cast(unsigned short, h11) << 16);
      if (pk0 == 0u) pk0 = READY0;   // -0|-0: numerically exact zero, nonzero bits
      if (pk1 == 0u) pk1 = READY0;
      unsigned* hbw = (unsigned*)(hb_d + (size_t)s * 13 * 1024 + blk * 1024
                                  + (w * 16 + fr) * 8) + fq;
      AS4(hbw, pk0);          // publish: store flight is the only handoff latency
      AS4(hbw + 256, pk1);
      *(unsigned*)(hout0 + (size_t)t * 800 + u0) = pk0;   // row-major for next GEMM
      *(unsigned*)(hout1 + (size_t)t * 800 + u0) = pk1;
    }
  }
}

// ---------------- tail ----------------
__global__ __launch_bounds__(256) void tail_k(const float* __restrict__ feat,
                                              const float* __restrict__ wo,
                                              float* __restrict__ s_h,
                                              float* __restrict__ s_m)
{
  const int r = blockIdx.x;
  const int tid = threadIdx.x;
  const float* fr = feat + (size_t)r * 1024;
  float sum = 0.f;
  const int n0 = tid * 4;
  #pragma unroll
  for (int j = 0; j < 4; ++j) sum += tanhf_(fr[n0 + j]) * wo[n0 + j];
  #pragma unroll
  for (int off = 32; off > 0; off >>= 1) sum += __shfl_down(sum, off, 64);
  __shared__ float red[4];
  if ((tid & 63) == 0) red[tid >> 6] = sum;
  __syncthreads();
  if (tid == 0)       s_h[r] = red[0] + red[1];
  else if (tid == 64) s_m[r] = red[2] + red[3];
}

__global__ void score_k(const float* __restrict__ s_h, const float* __restrict__ s_m,
                        const float* __restrict__ bo, float* __restrict__ out)
{
  const int bh = blockIdx.x;
  const int m = threadIdx.x;
  out[(size_t)bh * 128 + m] = s_h[bh] + s_m[(bh & ~127) + m] + bo[0];
}

// ---------------- launch ----------------
extern "C" void kernel_launch(void* const* d_in, const int* in_sizes, int n_in,
                              void* d_out, int out_size, void* d_ws, size_t ws_size,
                              hipStream_t stream)
{
  const int*   wt   = (const int*)d_in[0];
  const int*   pt   = (const int*)d_in[2];
  const float* we   = (const float*)d_in[3];
  const float* pe   = (const float*)d_in[4];
  const float* Wih0 = (const float*)d_in[5];
  const float* Whh0 = (const float*)d_in[6];
  const float* b0   = (const float*)d_in[7];
  const float* Wih1 = (const float*)d_in[8];
  const float* Whh1 = (const float*)d_in[9];
  const float* b1   = (const float*)d_in[10];
  const float* Wh   = (const float*)d_in[11];
  const float* bh   = (const float*)d_in[12];
  const float* Wm   = (const float*)d_in[13];
  const float* bm   = (const float*)d_in[14];
  const float* Wo   = (const float*)d_in[15];
  const float* bo   = (const float*)d_in[16];
  float* out = (float*)d_out;

  char* p = (char*)d_ws;
  auto alloc = [&](size_t bytes) { char* q = p; p += (bytes + 255) & ~(size_t)255; return q; };
  f16*   x0    = (f16*)alloc((size_t)4096 * K0P * 2);
  f16*   wihr0 = (f16*)alloc((size_t)GN * K0P * 2);
  f16*   wihr1 = (f16*)alloc((size_t)GN * 800 * 2);
  f16*   whhr0 = (f16*)alloc((size_t)2 * NBLK * 128 * WKP * 2);
  f16*   whhr1 = (f16*)alloc((size_t)2 * NBLK * 128 * WKP * 2);
  f16*   whm   = (f16*)alloc((size_t)1024 * 800 * 2);
  float* biasr0= (float*)alloc(GN * 4);
  float* biasr1= (float*)alloc(GN * 4);
  float* bhm   = (float*)alloc(1024 * 4);
  float* sh    = (float*)alloc(4096 * 4);
  float* sm    = (float*)alloc(4096 * 4);
  f16*   h1    = (f16*)alloc((size_t)4096 * 800 * 2);
  f16*   h2    = (f16*)alloc((size_t)4096 * 800 * 2);
  f16*   hB    = (f16*)alloc(HB_BYTES);          // [layer][d][s][blk][1024]
  float* gates = (float*)alloc((size_t)4096 * GN * 4);
  float* feat  = (float*)gates;   // gates dead before feature GEMM

  static bool attr_set = false;
  if (!attr_set) {
    hipFuncSetAttribute((const void*)lstm_mfma_k,
                        hipFuncAttributeMaxDynamicSharedMemorySize, SMEM_LSTM);
    attr_set = true;
  }

  // hB: zero real slots, READY0 only in never-written pad slots
  init_hb_k<<<512, 256, 0, stream>>>((unsigned*)hB, HB_BYTES / 4);
  embed_k<<<4096, 128, 0, stream>>>(wt, pt, we, pe, x0);
  wih_reorder_k<<<1024, 256, 0, stream>>>(Wih0, b0, wihr0, biasr0, 400, K0P);
  wih_reorder_k<<<1024, 256, 0, stream>>>(Wih1, b1, wihr1, biasr1, 800, 800);
  whh_reorder_k<<<1024, 256, 0, stream>>>(Whh0, whhr0);
  whh_reorder_k<<<1024, 256, 0, stream>>>(Whh1, whhr1);
  convpad_k<<<1024, 256, 0, stream>>>(Wh, whm, 512, 800, 800);
  convpad_k<<<1024, 256, 0, stream>>>(Wm, whm + (size_t)512 * 800, 512, 800, 800);
  biascat_k<<<1, 1024, 0, stream>>>(bh, bm, bhm);

  // layer 0
  gemm_f16_nt<<<dim3(26, 32), 256, 0, stream>>>(x0, wihr0, biasr0, gates, 4096, GN, K0P);
  lstm_mfma_k<<<26, 256, SMEM_LSTM, stream>>>(gates, whhr0, h1, hB);
  // layer 1
  gemm_f16_nt<<<dim3(26, 32), 256, 0, stream>>>(h1, wihr1, biasr1, gates, 4096, GN, 800);
  lstm_mfma_k<<<26, 256, SMEM_LSTM, stream>>>(gates, whhr1, h2, hB + HB1_ELEM);
  // features + scorer
  gemm_f16_nt<<<dim3(8, 32), 256, 0, stream>>>(h2, whm, bhm, feat, 4096, 1024, 800);
  tail_k<<<4096, 256, 0, stream>>>(feat, Wo, sh, sm);
  score_k<<<4096, 128, 0, stream>>>(sh, sm, bo, out);
}